// Round 2
// baseline (13.357 us; speedup 1.0000x reference)
//
#include <hip/hip_runtime.h>

// DAGGenome.get_active_mask — reachability from node 0 along left/right edges.
// Reference semantics: N-step scan with scatter-.set (duplicate indices:
// LAST index wins). Equivalent fixpoint: R[c] |= R[lp[c]] | R[rp[c]] where
// lp[c] = max{ i : left[i]==c && 0<=left[i]<N } (per-channel last parent).
// Output dtype: the reference returns a bool mask -> harness reads d_out as
// INT32 (0/1), not float (round-1 evidence: absmax == |1 - bits(1.0f)|).
//
// Single workgroup, everything in LDS:
//   tmp   : int[8192]  (32 KB)  — atomicMax scratch for lp, then rp;
//                                 first 8 KB later aliased as reach[] bytes,
//                                 byte 8192.. aliases the `changed` flag.
//   lp16  : short[8192] (16 KB) — last left-parent per node (-1 = none)
//   rp16  : short[8192] (16 KB) — last right-parent per node
// Total 64 KB static LDS.

#define NN  8192
#define NT  1024
#define PER (NN / NT)

__global__ __launch_bounds__(NT) void dag_reach_kernel(
    const int* __restrict__ left,
    const int* __restrict__ right,
    int* __restrict__ out)
{
    __shared__ int   tmp[NN];
    __shared__ short lp16[NN];
    __shared__ short rp16[NN];

    unsigned char* reach   = reinterpret_cast<unsigned char*>(tmp); // first 8 KB
    int*           changed = tmp + 2048;                            // byte 8192

    const int tid = threadIdx.x;

    // ---- preload edges (coalesced, 8 per thread) ----
    int lv[PER], rv[PER];
    #pragma unroll
    for (int k = 0; k < PER; ++k) {
        const int i = tid + k * NT;
        lv[k] = left[i];
        rv[k] = right[i];
    }

    // ---- phase A: lp = last-wins scatter of left ----
    #pragma unroll
    for (int k = 0; k < PER; ++k) tmp[tid + k * NT] = -1;
    __syncthreads();
    #pragma unroll
    for (int k = 0; k < PER; ++k) {
        const int i = tid + k * NT;
        const int l = lv[k];
        if (l >= 0 && l < NN) atomicMax(&tmp[l], i);
    }
    __syncthreads();
    #pragma unroll
    for (int k = 0; k < PER; ++k) {
        const int i = tid + k * NT;
        lp16[i] = (short)tmp[i];
    }
    __syncthreads();

    // ---- phase B: rp = last-wins scatter of right ----
    #pragma unroll
    for (int k = 0; k < PER; ++k) tmp[tid + k * NT] = -1;
    __syncthreads();
    #pragma unroll
    for (int k = 0; k < PER; ++k) {
        const int i = tid + k * NT;
        const int r = rv[k];
        if (r >= 0 && r < NN) atomicMax(&tmp[r], i);
    }
    __syncthreads();
    #pragma unroll
    for (int k = 0; k < PER; ++k) {
        const int i = tid + k * NT;
        rp16[i] = (short)tmp[i];
    }
    __syncthreads();

    // ---- phase C: init reach (aliases tmp's first 8 KB) ----
    #pragma unroll
    for (int k = 0; k < PER; ++k) {
        const int i = tid + k * NT;
        reach[i] = (i == 0) ? (unsigned char)1 : (unsigned char)0;
    }
    __syncthreads();

    // ---- phase D: fixpoint sweeps (pull-based) ----
    for (;;) {
        if (tid == 0) *changed = 0;
        __syncthreads();

        int mych = 0;
        #pragma unroll
        for (int k = 0; k < PER; ++k) {
            const int c = tid + k * NT;
            if (!reach[c]) {
                const int a = lp16[c];
                const int b = rp16[c];
                if ((a >= 0 && reach[a]) || (b >= 0 && reach[b])) {
                    reach[c] = 1;
                    mych = 1;
                }
            }
        }
        if (mych) *changed = 1;
        __syncthreads();

        const int done = (*changed == 0);
        __syncthreads();          // keep the read ordered before next reset
        if (done) break;          // uniform across the block
    }

    // ---- phase E: output as int32 0/1 (bool output dtype) ----
    #pragma unroll
    for (int k = 0; k < PER; ++k) {
        const int i = tid + k * NT;
        out[i] = reach[i] ? 1 : 0;
    }
}

extern "C" void kernel_launch(void* const* d_in, const int* in_sizes, int n_in,
                              void* d_out, int out_size, void* d_ws, size_t ws_size,
                              hipStream_t stream) {
    // setup_inputs order: thresholds, rules_left, rules_right, binary_ops, left, right
    const int* left  = (const int*)d_in[4];
    const int* right = (const int*)d_in[5];
    int* out = (int*)d_out;

    dag_reach_kernel<<<1, NT, 0, stream>>>(left, right, out);
}